// Round 1
// baseline (2683.001 us; speedup 1.0000x reference)
//
#include <hip/hip_runtime.h>

// Problem constants (validated at runtime from in_sizes)
//   N=100000 nodes, E=3200000 edges, F=128, C=32, H=24

// ---------------------------------------------------------------------------
// Dual GEMM for layer a: h = x@K1  (into A), p = x@K2 + b (into B)
// x: [n,128] f32. Block = 128 threads (2 waves), 64 nodes per block.
// Wave 0 (tid<64) computes K1 outputs, wave 1 computes K2 outputs, so the
// K pointer is wave-uniform -> compiler can scalarize K loads.
// LDS x tile padded to stride 129: read bank = (nl + k) % 32, 2-way (free).
// ---------------------------------------------------------------------------
__device__ __forceinline__ void gemm_row_f128(const float* xr,
                                              const float* __restrict__ K,
                                              float* acc) {
    for (int k = 0; k < 128; ++k) {
        float xv = xr[k];
        const float* Kr = K + k * 32;
        #pragma unroll
        for (int c = 0; c < 32; ++c) acc[c] = fmaf(xv, Kr[c], acc[c]);
    }
}

__global__ __launch_bounds__(128) void gemm_dual_a(
    const float* __restrict__ x, const float* __restrict__ K1,
    const float* __restrict__ K2, const float* __restrict__ bias,
    float* __restrict__ h, float* __restrict__ p, int n)
{
    __shared__ float xs[64 * 129];
    const int base = blockIdx.x * 64;

    // Stage 64 rows x 128 cols, coalesced float4 global reads.
    for (int i = threadIdx.x; i < 64 * 32; i += 128) {
        int r = i >> 5, c4 = i & 31;
        int node = base + r;
        float4 v = make_float4(0.f, 0.f, 0.f, 0.f);
        if (node < n) v = *(const float4*)(x + (size_t)node * 128 + c4 * 4);
        float* d = &xs[r * 129 + c4 * 4];
        d[0] = v.x; d[1] = v.y; d[2] = v.z; d[3] = v.w;
    }
    __syncthreads();

    const int nl = threadIdx.x & 63;
    const int node = base + nl;
    if (node >= n) return;

    float acc[32];
    #pragma unroll
    for (int c = 0; c < 32; ++c) acc[c] = 0.f;

    const float* xr = &xs[nl * 129];
    if (threadIdx.x < 64) {
        gemm_row_f128(xr, K1, acc);
        float* out = h + (size_t)node * 32;
        #pragma unroll
        for (int c4 = 0; c4 < 8; ++c4)
            *(float4*)(out + c4 * 4) = make_float4(acc[c4*4], acc[c4*4+1], acc[c4*4+2], acc[c4*4+3]);
    } else {
        gemm_row_f128(xr, K2, acc);
        #pragma unroll
        for (int c = 0; c < 32; ++c) acc[c] += bias[c];
        float* out = p + (size_t)node * 32;
        #pragma unroll
        for (int c4 = 0; c4 < 8; ++c4)
            *(float4*)(out + c4 * 4) = make_float4(acc[c4*4], acc[c4*4+1], acc[c4*4+2], acc[c4*4+3]);
    }
}

// ---------------------------------------------------------------------------
// Dual GEMM for layer b, fused with x1 = relu(agg + p) on the staging read.
// x1: [n,32]. Same wave-uniform-K structure, LDS stride 33.
// Writes h_b into A and p_b IN PLACE into B (rows are block-private).
// ---------------------------------------------------------------------------
__device__ __forceinline__ void gemm_row_f32(const float* xr,
                                             const float* __restrict__ K,
                                             float* acc) {
    for (int k = 0; k < 32; ++k) {
        float xv = xr[k];
        const float* Kr = K + k * 32;
        #pragma unroll
        for (int c = 0; c < 32; ++c) acc[c] = fmaf(xv, Kr[c], acc[c]);
    }
}

__global__ __launch_bounds__(128) void gemm_dual_b(
    const float* __restrict__ pa, const float* __restrict__ agg,
    const float* __restrict__ K1, const float* __restrict__ K2,
    const float* __restrict__ bias,
    float* __restrict__ h, float* __restrict__ p, int n)
{
    __shared__ float xs[64 * 33];
    const int base = blockIdx.x * 64;

    // Stage x1 = relu(pa + agg) for 64 rows, float4 reads.
    for (int i = threadIdx.x; i < 64 * 8; i += 128) {
        int r = i >> 3, c4 = i & 7;
        int node = base + r;
        float4 a = make_float4(0.f, 0.f, 0.f, 0.f);
        if (node < n) {
            float4 v1 = *(const float4*)(pa  + (size_t)node * 32 + c4 * 4);
            float4 v2 = *(const float4*)(agg + (size_t)node * 32 + c4 * 4);
            a.x = fmaxf(v1.x + v2.x, 0.f);
            a.y = fmaxf(v1.y + v2.y, 0.f);
            a.z = fmaxf(v1.z + v2.z, 0.f);
            a.w = fmaxf(v1.w + v2.w, 0.f);
        }
        float* d = &xs[r * 33 + c4 * 4];
        d[0] = a.x; d[1] = a.y; d[2] = a.z; d[3] = a.w;
    }
    __syncthreads();

    const int nl = threadIdx.x & 63;
    const int node = base + nl;
    if (node >= n) return;

    float acc[32];
    #pragma unroll
    for (int c = 0; c < 32; ++c) acc[c] = 0.f;

    const float* xr = &xs[nl * 33];
    if (threadIdx.x < 64) {
        gemm_row_f32(xr, K1, acc);
        float* out = h + (size_t)node * 32;
        #pragma unroll
        for (int c4 = 0; c4 < 8; ++c4)
            *(float4*)(out + c4 * 4) = make_float4(acc[c4*4], acc[c4*4+1], acc[c4*4+2], acc[c4*4+3]);
    } else {
        gemm_row_f32(xr, K2, acc);
        #pragma unroll
        for (int c = 0; c < 32; ++c) acc[c] += bias[c];
        float* out = p + (size_t)node * 32;
        #pragma unroll
        for (int c4 = 0; c4 < 8; ++c4)
            *(float4*)(out + c4 * 4) = make_float4(acc[c4*4], acc[c4*4+1], acc[c4*4+2], acc[c4*4+3]);
    }
}

// ---------------------------------------------------------------------------
// Edge scatter: agg[dst] += w * h[src].  8 threads per edge, float4 gather,
// hardware f32 atomics.
// ---------------------------------------------------------------------------
__global__ __launch_bounds__(256) void edge_scatter(
    const int* __restrict__ src, const int* __restrict__ dst,
    const float* __restrict__ w, const float* __restrict__ h,
    float* __restrict__ agg, int e)
{
    int t = blockIdx.x * 256 + threadIdx.x;
    int eid = t >> 3, q = t & 7;
    if (eid >= e) return;
    int s = src[eid];
    int d = dst[eid];
    float wv = w[eid];
    float4 hv = *(const float4*)(h + (size_t)s * 32 + q * 4);
    float* ap = agg + (size_t)d * 32 + q * 4;
    unsafeAtomicAdd(ap + 0, hv.x * wv);
    unsafeAtomicAdd(ap + 1, hv.y * wv);
    unsafeAtomicAdd(ap + 2, hv.z * wv);
    unsafeAtomicAdd(ap + 3, hv.w * wv);
}

// ---------------------------------------------------------------------------
// Global sum pool of x2 = relu(p + agg): pooled[c] = sum_n x2[n][c]
// ---------------------------------------------------------------------------
__global__ __launch_bounds__(256) void pool_kernel(
    const float* __restrict__ p, const float* __restrict__ agg,
    float* __restrict__ pooled, int n)
{
    const int ch = threadIdx.x & 31;
    const int r  = threadIdx.x >> 5;   // 0..7
    float acc = 0.f;
    for (int node = blockIdx.x * 8 + r; node < n; node += gridDim.x * 8) {
        size_t idx = (size_t)node * 32 + ch;
        acc += fmaxf(p[idx] + agg[idx], 0.f);
    }
    __shared__ float red[256];
    red[threadIdx.x] = acc;
    __syncthreads();
    if (threadIdx.x < 32) {
        float s = 0.f;
        #pragma unroll
        for (int i = 0; i < 8; ++i) s += red[i * 32 + ch];
        unsafeAtomicAdd(&pooled[ch], s);
    }
}

// ---------------------------------------------------------------------------
// Final dense epilogue: out = (pooled @ Wd1 + bd1) @ Wd2 + bd2
// ---------------------------------------------------------------------------
__global__ void dense_kernel(
    const float* __restrict__ pooled,
    const float* __restrict__ Wd1, const float* __restrict__ bd1,
    const float* __restrict__ Wd2, const float* __restrict__ bd2,
    float* __restrict__ out)
{
    int j = threadIdx.x;  // 64 threads = 1 wave; j<24 active
    float t = 0.f;
    if (j < 24) {
        t = bd1[j];
        #pragma unroll
        for (int c = 0; c < 32; ++c) t = fmaf(pooled[c], Wd1[c * 24 + j], t);
        t *= Wd2[j];
    }
    #pragma unroll
    for (int off = 32; off > 0; off >>= 1) t += __shfl_down(t, off, 64);
    if (j == 0) out[0] = t + bd2[0];
}

extern "C" void kernel_launch(void* const* d_in, const int* in_sizes, int n_in,
                              void* d_out, int out_size, void* d_ws, size_t ws_size,
                              hipStream_t stream) {
    const float* x   = (const float*)d_in[0];
    const int*   esrc= (const int*)d_in[1];
    const int*   edst= (const int*)d_in[2];
    const float* ew  = (const float*)d_in[3];
    const float* K1a = (const float*)d_in[4];
    const float* K2a = (const float*)d_in[5];
    const float* ba  = (const float*)d_in[6];
    const float* K1b = (const float*)d_in[7];
    const float* K2b = (const float*)d_in[8];
    const float* bb  = (const float*)d_in[9];
    const float* Wd1 = (const float*)d_in[10];
    const float* bd1 = (const float*)d_in[11];
    const float* Wd2 = (const float*)d_in[12];
    const float* bd2 = (const float*)d_in[13];

    const int n = in_sizes[0] / 128;   // 100000
    const int e = in_sizes[1];         // 3200000
    const size_t nc = (size_t)n * 32;

    float* A      = (float*)d_ws;      // h_a, then h_b
    float* B      = A + nc;            // p_a, then p_b (in-place)
    float* Cg     = B + nc;            // agg_a, then agg_b
    float* pooled = Cg + nc;           // [32]

    const int gemm_blocks = (n + 63) / 64;
    const int edge_blocks = (int)(((long long)e * 8 + 255) / 256);

    // Layer a
    hipMemsetAsync(Cg, 0, nc * sizeof(float), stream);
    gemm_dual_a<<<gemm_blocks, 128, 0, stream>>>(x, K1a, K2a, ba, A, B, n);
    edge_scatter<<<edge_blocks, 256, 0, stream>>>(esrc, edst, ew, A, Cg, e);

    // Layer b (x1 = relu(B + Cg) fused into staging)
    gemm_dual_b<<<gemm_blocks, 128, 0, stream>>>(B, Cg, K1b, K2b, bb, A, B, n);
    hipMemsetAsync(Cg, 0, nc * sizeof(float), stream);
    edge_scatter<<<edge_blocks, 256, 0, stream>>>(esrc, edst, ew, A, Cg, e);

    // Pool + dense epilogue
    hipMemsetAsync(pooled, 0, 32 * sizeof(float), stream);
    pool_kernel<<<1024, 256, 0, stream>>>(B, Cg, pooled, n);
    dense_kernel<<<1, 64, 0, stream>>>(pooled, Wd1, bd1, Wd2, bd2, (float*)d_out);
}

// Round 2
// 867.267 us; speedup vs baseline: 3.0936x; 3.0936x over previous
//
#include <hip/hip_runtime.h>

// Problem constants: N=100000 nodes, E=3200000 edges, F=128, C=32, H=24
//
// Pipeline (CSR-gather formulation, no f32 scatter atomics):
//   1. cnt[dst]++ (int atomics)            -> count_kernel
//   2. exclusive scan -> row[], cursor[]   -> scan_kernel (1 block)
//   3. bucket edges by dst: epack[pos]={src,w} -> csr_scatter_kernel
//   4. h_a=x@K1a, p_a=x@K2a+ba             -> gemm_dual_a
//   5. x1 = relu(gather(h_a)+p_a)          -> gather_x1_kernel (no atomics)
//   6. h_b=x1@K1b, p_b=x1@K2b+bb           -> gemm_dual_b
//   7. pooled += relu(gather(h_b)+p_b)     -> gather_pool_kernel (32 atomics/blk)
//   8. dense epilogue                      -> dense_kernel

// ---------------------------------------------------------------------------
// CSR build
// ---------------------------------------------------------------------------
__global__ __launch_bounds__(256) void count_kernel(
    const int* __restrict__ dst, int* __restrict__ cnt, int e)
{
    int i = blockIdx.x * 256 + threadIdx.x;
    if (i < e) atomicAdd(&cnt[dst[i]], 1);
}

__global__ __launch_bounds__(1024) void scan_kernel(
    int* __restrict__ cnt /* in: counts, out: cursor */,
    int* __restrict__ row, int n, int e)
{
    __shared__ int sums[1024];
    const int t = threadIdx.x;
    const int chunk = (n + 1023) >> 10;
    const int lo = t * chunk;
    const int hi = min(lo + chunk, n);

    int s = 0;
    for (int i = lo; i < hi; ++i) s += cnt[i];
    sums[t] = s;
    __syncthreads();
    // Hillis-Steele inclusive scan
    for (int off = 1; off < 1024; off <<= 1) {
        int u = (t >= off) ? sums[t - off] : 0;
        __syncthreads();
        sums[t] += u;
        __syncthreads();
    }
    int running = sums[t] - s;   // exclusive prefix
    for (int i = lo; i < hi; ++i) {
        int c = cnt[i];
        row[i] = running;
        cnt[i] = running;        // cursor starts at bucket base
        running += c;
    }
    if (t == 0) row[n] = e;
}

__global__ __launch_bounds__(256) void csr_scatter_kernel(
    const int* __restrict__ src, const int* __restrict__ dst,
    const float* __restrict__ w, int* __restrict__ cursor,
    unsigned long long* __restrict__ epack, int e)
{
    int i = blockIdx.x * 256 + threadIdx.x;
    if (i >= e) return;
    int d = dst[i];
    int pos = atomicAdd(&cursor[d], 1);
    unsigned int sb = (unsigned int)src[i];
    unsigned int wb = __float_as_uint(w[i]);
    epack[pos] = ((unsigned long long)wb << 32) | sb;
}

// ---------------------------------------------------------------------------
// Dual GEMM layer a: h = x@K1 (A), p = x@K2 + b (B).  x:[n,128]
// 128 thr = 2 waves, 64 nodes/block; K pointer wave-uniform.
// ---------------------------------------------------------------------------
__device__ __forceinline__ void gemm_row_f128(const float* xr,
                                              const float* __restrict__ K,
                                              float* acc) {
    for (int k = 0; k < 128; ++k) {
        float xv = xr[k];
        const float* Kr = K + k * 32;
        #pragma unroll
        for (int c = 0; c < 32; ++c) acc[c] = fmaf(xv, Kr[c], acc[c]);
    }
}

__global__ __launch_bounds__(128) void gemm_dual_a(
    const float* __restrict__ x, const float* __restrict__ K1,
    const float* __restrict__ K2, const float* __restrict__ bias,
    float* __restrict__ h, float* __restrict__ p, int n)
{
    __shared__ float xs[64 * 129];
    const int base = blockIdx.x * 64;

    for (int i = threadIdx.x; i < 64 * 32; i += 128) {
        int r = i >> 5, c4 = i & 31;
        int node = base + r;
        float4 v = make_float4(0.f, 0.f, 0.f, 0.f);
        if (node < n) v = *(const float4*)(x + (size_t)node * 128 + c4 * 4);
        float* d = &xs[r * 129 + c4 * 4];
        d[0] = v.x; d[1] = v.y; d[2] = v.z; d[3] = v.w;
    }
    __syncthreads();

    const int nl = threadIdx.x & 63;
    const int node = base + nl;
    if (node >= n) return;

    float acc[32];
    #pragma unroll
    for (int c = 0; c < 32; ++c) acc[c] = 0.f;

    const float* xr = &xs[nl * 129];
    if (threadIdx.x < 64) {
        gemm_row_f128(xr, K1, acc);
        float* out = h + (size_t)node * 32;
        #pragma unroll
        for (int c4 = 0; c4 < 8; ++c4)
            *(float4*)(out + c4 * 4) = make_float4(acc[c4*4], acc[c4*4+1], acc[c4*4+2], acc[c4*4+3]);
    } else {
        gemm_row_f128(xr, K2, acc);
        #pragma unroll
        for (int c = 0; c < 32; ++c) acc[c] += bias[c];
        float* out = p + (size_t)node * 32;
        #pragma unroll
        for (int c4 = 0; c4 < 8; ++c4)
            *(float4*)(out + c4 * 4) = make_float4(acc[c4*4], acc[c4*4+1], acc[c4*4+2], acc[c4*4+3]);
    }
}

// ---------------------------------------------------------------------------
// Dual GEMM layer b: reads x1:[n,32] directly (already relu'd by gather_x1).
// ---------------------------------------------------------------------------
__device__ __forceinline__ void gemm_row_f32(const float* xr,
                                             const float* __restrict__ K,
                                             float* acc) {
    for (int k = 0; k < 32; ++k) {
        float xv = xr[k];
        const float* Kr = K + k * 32;
        #pragma unroll
        for (int c = 0; c < 32; ++c) acc[c] = fmaf(xv, Kr[c], acc[c]);
    }
}

__global__ __launch_bounds__(128) void gemm_dual_b(
    const float* __restrict__ x1,
    const float* __restrict__ K1, const float* __restrict__ K2,
    const float* __restrict__ bias,
    float* __restrict__ h, float* __restrict__ p, int n)
{
    __shared__ float xs[64 * 33];
    const int base = blockIdx.x * 64;

    for (int i = threadIdx.x; i < 64 * 8; i += 128) {
        int r = i >> 3, c4 = i & 7;
        int node = base + r;
        float4 a = make_float4(0.f, 0.f, 0.f, 0.f);
        if (node < n) a = *(const float4*)(x1 + (size_t)node * 32 + c4 * 4);
        float* d = &xs[r * 33 + c4 * 4];
        d[0] = a.x; d[1] = a.y; d[2] = a.z; d[3] = a.w;
    }
    __syncthreads();

    const int nl = threadIdx.x & 63;
    const int node = base + nl;
    if (node >= n) return;

    float acc[32];
    #pragma unroll
    for (int c = 0; c < 32; ++c) acc[c] = 0.f;

    const float* xr = &xs[nl * 33];
    if (threadIdx.x < 64) {
        gemm_row_f32(xr, K1, acc);
        float* out = h + (size_t)node * 32;
        #pragma unroll
        for (int c4 = 0; c4 < 8; ++c4)
            *(float4*)(out + c4 * 4) = make_float4(acc[c4*4], acc[c4*4+1], acc[c4*4+2], acc[c4*4+3]);
    } else {
        gemm_row_f32(xr, K2, acc);
        #pragma unroll
        for (int c = 0; c < 32; ++c) acc[c] += bias[c];
        float* out = p + (size_t)node * 32;
        #pragma unroll
        for (int c4 = 0; c4 < 8; ++c4)
            *(float4*)(out + c4 * 4) = make_float4(acc[c4*4], acc[c4*4+1], acc[c4*4+2], acc[c4*4+3]);
    }
}

// ---------------------------------------------------------------------------
// CSR gather core: 8 threads per node (q = channel quad), 32 nodes/block.
// ---------------------------------------------------------------------------
__device__ __forceinline__ float4 gather_node(
    const int* __restrict__ row, const unsigned long long* __restrict__ epack,
    const float* __restrict__ h, int node, int q)
{
    int r0 = row[node], r1 = row[node + 1];
    float4 acc = make_float4(0.f, 0.f, 0.f, 0.f);
    for (int e = r0; e < r1; ++e) {
        unsigned long long pk = epack[e];
        int s = (int)(unsigned int)(pk & 0xFFFFFFFFu);
        float wv = __uint_as_float((unsigned int)(pk >> 32));
        float4 hv = *(const float4*)(h + (size_t)s * 32 + q * 4);
        acc.x = fmaf(wv, hv.x, acc.x);
        acc.y = fmaf(wv, hv.y, acc.y);
        acc.z = fmaf(wv, hv.z, acc.z);
        acc.w = fmaf(wv, hv.w, acc.w);
    }
    return acc;
}

// x1 = relu(agg + p), written coalesced.
__global__ __launch_bounds__(256) void gather_x1_kernel(
    const int* __restrict__ row, const unsigned long long* __restrict__ epack,
    const float* __restrict__ h, const float* __restrict__ p,
    float* __restrict__ x1, int n)
{
    const int q = threadIdx.x & 7;
    const int node = blockIdx.x * 32 + (threadIdx.x >> 3);
    if (node >= n) return;
    float4 acc = gather_node(row, epack, h, node, q);
    const float4 pv = *(const float4*)(p + (size_t)node * 32 + q * 4);
    float4 o;
    o.x = fmaxf(acc.x + pv.x, 0.f);
    o.y = fmaxf(acc.y + pv.y, 0.f);
    o.z = fmaxf(acc.z + pv.z, 0.f);
    o.w = fmaxf(acc.w + pv.w, 0.f);
    *(float4*)(x1 + (size_t)node * 32 + q * 4) = o;
}

// pooled[c] += sum over nodes of relu(agg + p)[c]; agg/x2 never materialized.
__global__ __launch_bounds__(256) void gather_pool_kernel(
    const int* __restrict__ row, const unsigned long long* __restrict__ epack,
    const float* __restrict__ h, const float* __restrict__ p,
    float* __restrict__ pooled, int n)
{
    const int q = threadIdx.x & 7;
    const int ln = threadIdx.x >> 3;
    const int node = blockIdx.x * 32 + ln;

    float4 o = make_float4(0.f, 0.f, 0.f, 0.f);
    if (node < n) {
        float4 acc = gather_node(row, epack, h, node, q);
        const float4 pv = *(const float4*)(p + (size_t)node * 32 + q * 4);
        o.x = fmaxf(acc.x + pv.x, 0.f);
        o.y = fmaxf(acc.y + pv.y, 0.f);
        o.z = fmaxf(acc.z + pv.z, 0.f);
        o.w = fmaxf(acc.w + pv.w, 0.f);
    }
    __shared__ float red[256][4];
    red[threadIdx.x][0] = o.x; red[threadIdx.x][1] = o.y;
    red[threadIdx.x][2] = o.z; red[threadIdx.x][3] = o.w;
    __syncthreads();
    if (threadIdx.x < 32) {
        const int c = threadIdx.x;          // channel
        const int cq = c >> 2, cj = c & 3;
        float s = 0.f;
        #pragma unroll
        for (int l = 0; l < 32; ++l) s += red[l * 8 + cq][cj];
        unsafeAtomicAdd(&pooled[c], s);
    }
}

// ---------------------------------------------------------------------------
// Fallback scatter path (used only if ws_size too small for CSR buffers)
// ---------------------------------------------------------------------------
__global__ __launch_bounds__(256) void edge_scatter(
    const int* __restrict__ src, const int* __restrict__ dst,
    const float* __restrict__ w, const float* __restrict__ h,
    float* __restrict__ agg, int e)
{
    int t = blockIdx.x * 256 + threadIdx.x;
    int eid = t >> 3, q = t & 7;
    if (eid >= e) return;
    int s = src[eid];
    int d = dst[eid];
    float wv = w[eid];
    float4 hv = *(const float4*)(h + (size_t)s * 32 + q * 4);
    float* ap = agg + (size_t)d * 32 + q * 4;
    unsafeAtomicAdd(ap + 0, hv.x * wv);
    unsafeAtomicAdd(ap + 1, hv.y * wv);
    unsafeAtomicAdd(ap + 2, hv.z * wv);
    unsafeAtomicAdd(ap + 3, hv.w * wv);
}

__global__ __launch_bounds__(256) void relu_add_kernel(
    const float* __restrict__ a, const float* __restrict__ b,
    float* __restrict__ o, size_t m)
{
    size_t i = (size_t)blockIdx.x * 256 + threadIdx.x;
    if (i < m) o[i] = fmaxf(a[i] + b[i], 0.f);
}

__global__ __launch_bounds__(256) void pool_kernel(
    const float* __restrict__ p, const float* __restrict__ agg,
    float* __restrict__ pooled, int n)
{
    const int ch = threadIdx.x & 31;
    const int r  = threadIdx.x >> 5;
    float acc = 0.f;
    for (int node = blockIdx.x * 8 + r; node < n; node += gridDim.x * 8) {
        size_t idx = (size_t)node * 32 + ch;
        acc += fmaxf(p[idx] + agg[idx], 0.f);
    }
    __shared__ float red[256];
    red[threadIdx.x] = acc;
    __syncthreads();
    if (threadIdx.x < 32) {
        float s = 0.f;
        #pragma unroll
        for (int i = 0; i < 8; ++i) s += red[i * 32 + ch];
        unsafeAtomicAdd(&pooled[ch], s);
    }
}

// ---------------------------------------------------------------------------
// Dense epilogue: out = (pooled @ Wd1 + bd1) @ Wd2 + bd2
// ---------------------------------------------------------------------------
__global__ void dense_kernel(
    const float* __restrict__ pooled,
    const float* __restrict__ Wd1, const float* __restrict__ bd1,
    const float* __restrict__ Wd2, const float* __restrict__ bd2,
    float* __restrict__ out)
{
    int j = threadIdx.x;
    float t = 0.f;
    if (j < 24) {
        t = bd1[j];
        #pragma unroll
        for (int c = 0; c < 32; ++c) t = fmaf(pooled[c], Wd1[c * 24 + j], t);
        t *= Wd2[j];
    }
    #pragma unroll
    for (int off = 32; off > 0; off >>= 1) t += __shfl_down(t, off, 64);
    if (j == 0) out[0] = t + bd2[0];
}

extern "C" void kernel_launch(void* const* d_in, const int* in_sizes, int n_in,
                              void* d_out, int out_size, void* d_ws, size_t ws_size,
                              hipStream_t stream) {
    const float* x   = (const float*)d_in[0];
    const int*   esrc= (const int*)d_in[1];
    const int*   edst= (const int*)d_in[2];
    const float* ew  = (const float*)d_in[3];
    const float* K1a = (const float*)d_in[4];
    const float* K2a = (const float*)d_in[5];
    const float* ba  = (const float*)d_in[6];
    const float* K1b = (const float*)d_in[7];
    const float* K2b = (const float*)d_in[8];
    const float* bb  = (const float*)d_in[9];
    const float* Wd1 = (const float*)d_in[10];
    const float* bd1 = (const float*)d_in[11];
    const float* Wd2 = (const float*)d_in[12];
    const float* bd2 = (const float*)d_in[13];

    const int n = in_sizes[0] / 128;   // 100000
    const int e = in_sizes[1];         // 3200000
    const size_t nc = (size_t)n * 32;

    const size_t need = (size_t)e * 8              // epack
                      + 3 * nc * 4                 // A, B, Cg
                      + 32 * 4                     // pooled
                      + (size_t)(n + 1) * 4        // row
                      + (size_t)n * 4;             // cnt/cursor

    const int gemm_blocks   = (n + 63) / 64;
    const int edge_blocks_1 = (e + 255) / 256;
    const int gather_blocks = (n + 31) / 32;

    if (ws_size >= need) {
        // ---- CSR gather path ----
        unsigned long long* epack = (unsigned long long*)d_ws;   // 8B aligned @0
        float* A      = (float*)(epack + e);
        float* B      = A + nc;
        float* Cg     = B + nc;
        float* pooled = Cg + nc;
        int*   rowp   = (int*)(pooled + 32);
        int*   cnt    = rowp + (n + 1);

        hipMemsetAsync(cnt, 0, (size_t)n * 4, stream);
        hipMemsetAsync(pooled, 0, 32 * 4, stream);
        count_kernel<<<edge_blocks_1, 256, 0, stream>>>(edst, cnt, e);
        scan_kernel<<<1, 1024, 0, stream>>>(cnt, rowp, n, e);
        csr_scatter_kernel<<<edge_blocks_1, 256, 0, stream>>>(esrc, edst, ew, cnt, epack, e);

        gemm_dual_a<<<gemm_blocks, 128, 0, stream>>>(x, K1a, K2a, ba, A, B, n);
        gather_x1_kernel<<<gather_blocks, 256, 0, stream>>>(rowp, epack, A, B, Cg, n);
        gemm_dual_b<<<gemm_blocks, 128, 0, stream>>>(Cg, K1b, K2b, bb, A, B, n);
        gather_pool_kernel<<<gather_blocks, 256, 0, stream>>>(rowp, epack, A, B, pooled, n);
        dense_kernel<<<1, 64, 0, stream>>>(pooled, Wd1, bd1, Wd2, bd2, (float*)d_out);
    } else {
        // ---- fallback: atomic scatter path (previous round) ----
        float* A      = (float*)d_ws;
        float* B      = A + nc;
        float* Cg     = B + nc;
        float* pooled = Cg + nc;
        const int edge_blocks_8 = (int)(((long long)e * 8 + 255) / 256);

        hipMemsetAsync(Cg, 0, nc * 4, stream);
        gemm_dual_a<<<gemm_blocks, 128, 0, stream>>>(x, K1a, K2a, ba, A, B, n);
        edge_scatter<<<edge_blocks_8, 256, 0, stream>>>(esrc, edst, ew, A, Cg, e);
        relu_add_kernel<<<(int)((nc + 255) / 256), 256, 0, stream>>>(B, Cg, B, nc);
        gemm_dual_b<<<gemm_blocks, 128, 0, stream>>>(B, K1b, K2b, bb, A, Cg, n);
        hipMemsetAsync(B, 0, nc * 4, stream);
        edge_scatter<<<edge_blocks_8, 256, 0, stream>>>(esrc, edst, ew, A, B, e);
        hipMemsetAsync(pooled, 0, 32 * 4, stream);
        pool_kernel<<<1024, 256, 0, stream>>>(Cg, B, pooled, n);
        dense_kernel<<<1, 64, 0, stream>>>(pooled, Wd1, bd1, Wd2, bd2, (float*)d_out);
    }
}

// Round 3
// 344.714 us; speedup vs baseline: 7.7833x; 2.5159x over previous
//
#include <hip/hip_runtime.h>

// Problem constants: N=100000 nodes, E=3200000 edges, F=128, C=32, H=24
//
// Pipeline:
//   1. build_runs:    chunk 16384 edges/block, LDS counting-sort by bucket
//                     (dst>>8), write bucket-grouped run into the block's own
//                     contiguous window (single-CU writes -> L2 merges lines)
//   2. bucket_scan:   exclusive scan of bucket totals
//   3. sort_buckets:  block per bucket, gather run segments, LDS counting-sort
//                     by dst&255, emit dst-sorted epack + CSR row[] directly
//   4. gemm_dual_a:   h_a = x@K1a, p_a = x@K2a + ba
//   5. gather_x1:     x1 = relu(csr_gather(h_a) + p_a)      (no atomics)
//   6. gemm_dual_b:   h_b = x1@K1b, p_b = x1@K2b + bb
//   7. gather_pool:   pooled += relu(csr_gather(h_b) + p_b) (32 atomics/blk)
//   8. dense epilogue
//
// epack record: low = src | (dst&255)<<20 ; high = f32 bits of w  (n < 2^20)

#define CHUNK 16384
#define NPB   256   // nodes per bucket

// ---------------------------------------------------------------------------
__global__ __launch_bounds__(256) void build_runs_kernel(
    const int* __restrict__ src, const int* __restrict__ dst,
    const float* __restrict__ w,
    unsigned long long* __restrict__ etmp, int* __restrict__ runoffT,
    int* __restrict__ bucket_cnt, int e, int nruns, int nb)
{
    __shared__ int hist[512];
    __shared__ int scn[256];
    __shared__ int cur[512];
    const int r = blockIdx.x, tid = threadIdx.x;
    const int base = r * CHUNK;
    const int cnt = min(CHUNK, e - base);

    hist[tid] = 0; hist[tid + 256] = 0;
    __syncthreads();
    for (int i = tid; i < cnt; i += 256) atomicAdd(&hist[dst[base + i] >> 8], 1);
    __syncthreads();

    // exclusive scan of hist[0..511] with 256 threads (2 elems/thread)
    int a0 = hist[2 * tid], a1 = hist[2 * tid + 1], s = a0 + a1;
    scn[tid] = s; __syncthreads();
    for (int off = 1; off < 256; off <<= 1) {
        int u = (tid >= off) ? scn[tid - off] : 0;
        __syncthreads(); scn[tid] += u; __syncthreads();
    }
    int ex = scn[tid] - s;
    cur[2 * tid] = ex; cur[2 * tid + 1] = ex + a0;
    __syncthreads();

    // metadata: runoffT[b][r] = global start of (run r, bucket b); b in [0,nb]
    for (int b = tid; b <= nb; b += 256)
        runoffT[(size_t)b * nruns + r] = base + cur[b];
    for (int b = tid; b < nb; b += 256)
        if (hist[b]) atomicAdd(&bucket_cnt[b], hist[b]);
    __syncthreads();

    // scatter into this block's own window (random within 128KB -> L2 merges)
    for (int i = tid; i < cnt; i += 256) {
        int d = dst[base + i];
        int bq = d >> 8;
        int pos = atomicAdd(&cur[bq], 1);
        unsigned int lo = (unsigned int)src[base + i] | ((unsigned int)(d & 255) << 20);
        unsigned long long pk = (unsigned long long)lo |
                                ((unsigned long long)__float_as_uint(w[base + i]) << 32);
        etmp[base + pos] = pk;
    }
}

__global__ __launch_bounds__(512) void bucket_scan_kernel(
    const int* __restrict__ cnt, int* __restrict__ basep, int nb, int e)
{
    __shared__ int s[512];
    int t = threadIdx.x;
    int v = (t < nb) ? cnt[t] : 0;
    s[t] = v; __syncthreads();
    for (int off = 1; off < 512; off <<= 1) {
        int u = (t >= off) ? s[t - off] : 0;
        __syncthreads(); s[t] += u; __syncthreads();
    }
    if (t < nb) basep[t] = s[t] - v;
    if (t == 0) basep[nb] = e;
}

__global__ __launch_bounds__(256) void sort_buckets_kernel(
    const unsigned long long* __restrict__ etmp,
    const int* __restrict__ runoffT, const int* __restrict__ bbase,
    unsigned long long* __restrict__ epack, int* __restrict__ row,
    int n, int e, int nruns, int nb)
{
    const int b = blockIdx.x, tid = threadIdx.x;
    __shared__ int hist[256];
    __shared__ int scn[256];
    __shared__ int cur[256];
    hist[tid] = 0;
    __syncthreads();

    const int wave = tid >> 6, lane = tid & 63, grp = lane >> 3, sub = lane & 7;
    const int stream = wave * 8 + grp;            // 0..31 concurrent segment streams
    const int* rs = runoffT + (size_t)b * nruns;
    const int* re = runoffT + (size_t)(b + 1) * nruns;

    for (int r = stream; r < nruns; r += 32) {
        int s0 = rs[r], s1 = re[r];
        for (int i = s0 + sub; i < s1; i += 8)
            atomicAdd(&hist[(int)((etmp[i] >> 20) & 255)], 1);
    }
    __syncthreads();

    int v = hist[tid];
    scn[tid] = v; __syncthreads();
    for (int off = 1; off < 256; off <<= 1) {
        int u = (tid >= off) ? scn[tid - off] : 0;
        __syncthreads(); scn[tid] += u; __syncthreads();
    }
    int ex = scn[tid] - v;
    cur[tid] = ex;
    const int base0 = bbase[b];
    const int node = b * NPB + tid;
    if (node < n) row[node] = base0 + ex;
    if (b == nb - 1 && tid == 0) row[n] = e;
    __syncthreads();

    for (int r = stream; r < nruns; r += 32) {
        int s0 = rs[r], s1 = re[r];
        for (int i = s0 + sub; i < s1; i += 8) {
            unsigned long long pk = etmp[i];
            int pos = atomicAdd(&cur[(int)((pk >> 20) & 255)], 1);
            epack[(size_t)base0 + pos] = pk;   // random within 64KB own-block window
        }
    }
}

// ---------------------------------------------------------------------------
// Dual GEMM layer a: h = x@K1 (A), p = x@K2 + b (B).  x:[n,128]
// ---------------------------------------------------------------------------
__device__ __forceinline__ void gemm_row_f128(const float* xr,
                                              const float* __restrict__ K,
                                              float* acc) {
    for (int k = 0; k < 128; ++k) {
        float xv = xr[k];
        const float* Kr = K + k * 32;
        #pragma unroll
        for (int c = 0; c < 32; ++c) acc[c] = fmaf(xv, Kr[c], acc[c]);
    }
}

__global__ __launch_bounds__(128) void gemm_dual_a(
    const float* __restrict__ x, const float* __restrict__ K1,
    const float* __restrict__ K2, const float* __restrict__ bias,
    float* __restrict__ h, float* __restrict__ p, int n)
{
    __shared__ float xs[64 * 129];
    const int base = blockIdx.x * 64;

    for (int i = threadIdx.x; i < 64 * 32; i += 128) {
        int r = i >> 5, c4 = i & 31;
        int node = base + r;
        float4 v = make_float4(0.f, 0.f, 0.f, 0.f);
        if (node < n) v = *(const float4*)(x + (size_t)node * 128 + c4 * 4);
        float* d = &xs[r * 129 + c4 * 4];
        d[0] = v.x; d[1] = v.y; d[2] = v.z; d[3] = v.w;
    }
    __syncthreads();

    const int nl = threadIdx.x & 63;
    const int node = base + nl;
    if (node >= n) return;

    float acc[32];
    #pragma unroll
    for (int c = 0; c < 32; ++c) acc[c] = 0.f;

    const float* xr = &xs[nl * 129];
    if (threadIdx.x < 64) {
        gemm_row_f128(xr, K1, acc);
        float* out = h + (size_t)node * 32;
        #pragma unroll
        for (int c4 = 0; c4 < 8; ++c4)
            *(float4*)(out + c4 * 4) = make_float4(acc[c4*4], acc[c4*4+1], acc[c4*4+2], acc[c4*4+3]);
    } else {
        gemm_row_f128(xr, K2, acc);
        #pragma unroll
        for (int c = 0; c < 32; ++c) acc[c] += bias[c];
        float* out = p + (size_t)node * 32;
        #pragma unroll
        for (int c4 = 0; c4 < 8; ++c4)
            *(float4*)(out + c4 * 4) = make_float4(acc[c4*4], acc[c4*4+1], acc[c4*4+2], acc[c4*4+3]);
    }
}

// ---------------------------------------------------------------------------
// Dual GEMM layer b: reads x1:[n,32] (already relu'd).
// ---------------------------------------------------------------------------
__device__ __forceinline__ void gemm_row_f32(const float* xr,
                                             const float* __restrict__ K,
                                             float* acc) {
    for (int k = 0; k < 32; ++k) {
        float xv = xr[k];
        const float* Kr = K + k * 32;
        #pragma unroll
        for (int c = 0; c < 32; ++c) acc[c] = fmaf(xv, Kr[c], acc[c]);
    }
}

__global__ __launch_bounds__(128) void gemm_dual_b(
    const float* __restrict__ x1,
    const float* __restrict__ K1, const float* __restrict__ K2,
    const float* __restrict__ bias,
    float* __restrict__ h, float* __restrict__ p, int n)
{
    __shared__ float xs[64 * 33];
    const int base = blockIdx.x * 64;

    for (int i = threadIdx.x; i < 64 * 8; i += 128) {
        int r = i >> 3, c4 = i & 7;
        int node = base + r;
        float4 a = make_float4(0.f, 0.f, 0.f, 0.f);
        if (node < n) a = *(const float4*)(x1 + (size_t)node * 32 + c4 * 4);
        float* d = &xs[r * 33 + c4 * 4];
        d[0] = a.x; d[1] = a.y; d[2] = a.z; d[3] = a.w;
    }
    __syncthreads();

    const int nl = threadIdx.x & 63;
    const int node = base + nl;
    if (node >= n) return;

    float acc[32];
    #pragma unroll
    for (int c = 0; c < 32; ++c) acc[c] = 0.f;

    const float* xr = &xs[nl * 33];
    if (threadIdx.x < 64) {
        gemm_row_f32(xr, K1, acc);
        float* out = h + (size_t)node * 32;
        #pragma unroll
        for (int c4 = 0; c4 < 8; ++c4)
            *(float4*)(out + c4 * 4) = make_float4(acc[c4*4], acc[c4*4+1], acc[c4*4+2], acc[c4*4+3]);
    } else {
        gemm_row_f32(xr, K2, acc);
        #pragma unroll
        for (int c = 0; c < 32; ++c) acc[c] += bias[c];
        float* out = p + (size_t)node * 32;
        #pragma unroll
        for (int c4 = 0; c4 < 8; ++c4)
            *(float4*)(out + c4 * 4) = make_float4(acc[c4*4], acc[c4*4+1], acc[c4*4+2], acc[c4*4+3]);
    }
}

// ---------------------------------------------------------------------------
// CSR gather core: 8 threads/node, 2-way unrolled for load ILP.
// ---------------------------------------------------------------------------
__device__ __forceinline__ float4 gather_node(
    const int* __restrict__ row, const unsigned long long* __restrict__ epack,
    const float* __restrict__ h, int node, int q)
{
    int r0 = row[node], r1 = row[node + 1];
    float4 a = make_float4(0.f, 0.f, 0.f, 0.f);
    float4 b = make_float4(0.f, 0.f, 0.f, 0.f);
    int i = r0;
    for (; i + 1 < r1; i += 2) {
        unsigned long long p0 = epack[i], p1 = epack[i + 1];
        int s0 = (int)(p0 & 0xFFFFFu);
        int s1 = (int)(p1 & 0xFFFFFu);
        float w0 = __uint_as_float((unsigned int)(p0 >> 32));
        float w1 = __uint_as_float((unsigned int)(p1 >> 32));
        float4 h0 = *(const float4*)(h + (size_t)s0 * 32 + q * 4);
        float4 h1 = *(const float4*)(h + (size_t)s1 * 32 + q * 4);
        a.x = fmaf(w0, h0.x, a.x); a.y = fmaf(w0, h0.y, a.y);
        a.z = fmaf(w0, h0.z, a.z); a.w = fmaf(w0, h0.w, a.w);
        b.x = fmaf(w1, h1.x, b.x); b.y = fmaf(w1, h1.y, b.y);
        b.z = fmaf(w1, h1.z, b.z); b.w = fmaf(w1, h1.w, b.w);
    }
    if (i < r1) {
        unsigned long long p0 = epack[i];
        int s0 = (int)(p0 & 0xFFFFFu);
        float w0 = __uint_as_float((unsigned int)(p0 >> 32));
        float4 h0 = *(const float4*)(h + (size_t)s0 * 32 + q * 4);
        a.x = fmaf(w0, h0.x, a.x); a.y = fmaf(w0, h0.y, a.y);
        a.z = fmaf(w0, h0.z, a.z); a.w = fmaf(w0, h0.w, a.w);
    }
    a.x += b.x; a.y += b.y; a.z += b.z; a.w += b.w;
    return a;
}

__global__ __launch_bounds__(256) void gather_x1_kernel(
    const int* __restrict__ row, const unsigned long long* __restrict__ epack,
    const float* __restrict__ h, const float* __restrict__ p,
    float* __restrict__ x1, int n)
{
    const int q = threadIdx.x & 7;
    const int node = blockIdx.x * 32 + (threadIdx.x >> 3);
    if (node >= n) return;
    float4 acc = gather_node(row, epack, h, node, q);
    const float4 pv = *(const float4*)(p + (size_t)node * 32 + q * 4);
    float4 o;
    o.x = fmaxf(acc.x + pv.x, 0.f);
    o.y = fmaxf(acc.y + pv.y, 0.f);
    o.z = fmaxf(acc.z + pv.z, 0.f);
    o.w = fmaxf(acc.w + pv.w, 0.f);
    *(float4*)(x1 + (size_t)node * 32 + q * 4) = o;
}

__global__ __launch_bounds__(256) void gather_pool_kernel(
    const int* __restrict__ row, const unsigned long long* __restrict__ epack,
    const float* __restrict__ h, const float* __restrict__ p,
    float* __restrict__ pooled, int n)
{
    const int q = threadIdx.x & 7;
    const int node = blockIdx.x * 32 + (threadIdx.x >> 3);

    float4 o = make_float4(0.f, 0.f, 0.f, 0.f);
    if (node < n) {
        float4 acc = gather_node(row, epack, h, node, q);
        const float4 pv = *(const float4*)(p + (size_t)node * 32 + q * 4);
        o.x = fmaxf(acc.x + pv.x, 0.f);
        o.y = fmaxf(acc.y + pv.y, 0.f);
        o.z = fmaxf(acc.z + pv.z, 0.f);
        o.w = fmaxf(acc.w + pv.w, 0.f);
    }
    __shared__ float red[256][4];
    red[threadIdx.x][0] = o.x; red[threadIdx.x][1] = o.y;
    red[threadIdx.x][2] = o.z; red[threadIdx.x][3] = o.w;
    __syncthreads();
    if (threadIdx.x < 32) {
        const int c = threadIdx.x;
        const int cq = c >> 2, cj = c & 3;
        float s = 0.f;
        #pragma unroll
        for (int l = 0; l < 32; ++l) s += red[l * 8 + cq][cj];
        unsafeAtomicAdd(&pooled[c], s);
    }
}

// ---------------------------------------------------------------------------
// Fallback (ws too small): atomic scatter path.
// ---------------------------------------------------------------------------
__global__ __launch_bounds__(256) void edge_scatter(
    const int* __restrict__ src, const int* __restrict__ dst,
    const float* __restrict__ w, const float* __restrict__ h,
    float* __restrict__ agg, int e)
{
    int t = blockIdx.x * 256 + threadIdx.x;
    int eid = t >> 3, q = t & 7;
    if (eid >= e) return;
    int s = src[eid];
    int d = dst[eid];
    float wv = w[eid];
    float4 hv = *(const float4*)(h + (size_t)s * 32 + q * 4);
    float* ap = agg + (size_t)d * 32 + q * 4;
    unsafeAtomicAdd(ap + 0, hv.x * wv);
    unsafeAtomicAdd(ap + 1, hv.y * wv);
    unsafeAtomicAdd(ap + 2, hv.z * wv);
    unsafeAtomicAdd(ap + 3, hv.w * wv);
}

__global__ __launch_bounds__(256) void relu_add_kernel(
    const float* __restrict__ a, const float* __restrict__ b,
    float* __restrict__ o, size_t m)
{
    size_t i = (size_t)blockIdx.x * 256 + threadIdx.x;
    if (i < m) o[i] = fmaxf(a[i] + b[i], 0.f);
}

__global__ __launch_bounds__(256) void pool_kernel(
    const float* __restrict__ p, const float* __restrict__ agg,
    float* __restrict__ pooled, int n)
{
    const int ch = threadIdx.x & 31;
    const int r  = threadIdx.x >> 5;
    float acc = 0.f;
    for (int node = blockIdx.x * 8 + r; node < n; node += gridDim.x * 8) {
        size_t idx = (size_t)node * 32 + ch;
        acc += fmaxf(p[idx] + agg[idx], 0.f);
    }
    __shared__ float red[256];
    red[threadIdx.x] = acc;
    __syncthreads();
    if (threadIdx.x < 32) {
        float s = 0.f;
        #pragma unroll
        for (int i = 0; i < 8; ++i) s += red[i * 32 + ch];
        unsafeAtomicAdd(&pooled[ch], s);
    }
}

__global__ void dense_kernel(
    const float* __restrict__ pooled,
    const float* __restrict__ Wd1, const float* __restrict__ bd1,
    const float* __restrict__ Wd2, const float* __restrict__ bd2,
    float* __restrict__ out)
{
    int j = threadIdx.x;
    float t = 0.f;
    if (j < 24) {
        t = bd1[j];
        #pragma unroll
        for (int c = 0; c < 32; ++c) t = fmaf(pooled[c], Wd1[c * 24 + j], t);
        t *= Wd2[j];
    }
    #pragma unroll
    for (int off = 32; off > 0; off >>= 1) t += __shfl_down(t, off, 64);
    if (j == 0) out[0] = t + bd2[0];
}

extern "C" void kernel_launch(void* const* d_in, const int* in_sizes, int n_in,
                              void* d_out, int out_size, void* d_ws, size_t ws_size,
                              hipStream_t stream) {
    const float* x   = (const float*)d_in[0];
    const int*   esrc= (const int*)d_in[1];
    const int*   edst= (const int*)d_in[2];
    const float* ew  = (const float*)d_in[3];
    const float* K1a = (const float*)d_in[4];
    const float* K2a = (const float*)d_in[5];
    const float* ba  = (const float*)d_in[6];
    const float* K1b = (const float*)d_in[7];
    const float* K2b = (const float*)d_in[8];
    const float* bb  = (const float*)d_in[9];
    const float* Wd1 = (const float*)d_in[10];
    const float* bd1 = (const float*)d_in[11];
    const float* Wd2 = (const float*)d_in[12];
    const float* bd2 = (const float*)d_in[13];

    const int n = in_sizes[0] / 128;   // 100000
    const int e = in_sizes[1];         // 3200000
    const size_t nc = (size_t)n * 32;
    const int nb = (n + NPB - 1) / NPB;            // 391
    const int nruns = (e + CHUNK - 1) / CHUNK;     // 196

    // ws layout:
    //   epack  [e]  ull
    //   etmp   [e]  ull  <-- reused as A[nc], B[nc] after sort_buckets
    //   Cg     [nc] f32
    //   pooled [32] f32
    //   row    [n+1] int
    //   bucket_cnt [nb] int
    //   bucket_base[nb+1] int
    //   runoffT [(nb+1)*nruns] int
    const size_t etmp_bytes = (size_t)e * 8 > 2 * nc * 4 ? (size_t)e * 8 : 2 * nc * 4;
    const size_t need = (size_t)e * 8 + etmp_bytes + nc * 4 + 32 * 4
                      + (size_t)(n + 1) * 4 + (size_t)nb * 4
                      + (size_t)(nb + 1) * 4 + (size_t)(nb + 1) * nruns * 4;

    const int gemm_blocks   = (n + 63) / 64;
    const int gather_blocks = (n + 31) / 32;

    if (ws_size >= need) {
        char* wp = (char*)d_ws;
        unsigned long long* epack = (unsigned long long*)wp;  wp += (size_t)e * 8;
        unsigned long long* etmp  = (unsigned long long*)wp;
        float* A = (float*)etmp;              // aliases etmp after sort
        float* B = A + nc;                    wp += etmp_bytes;
        float* Cg = (float*)wp;               wp += nc * 4;
        float* pooled = (float*)wp;           wp += 32 * 4;
        int* row = (int*)wp;                  wp += (size_t)(n + 1) * 4;
        int* bucket_cnt = (int*)wp;           wp += (size_t)nb * 4;
        int* bucket_base = (int*)wp;          wp += (size_t)(nb + 1) * 4;
        int* runoffT = (int*)wp;

        hipMemsetAsync(bucket_cnt, 0, (size_t)nb * 4, stream);
        hipMemsetAsync(pooled, 0, 32 * 4, stream);

        build_runs_kernel<<<nruns, 256, 0, stream>>>(esrc, edst, ew, etmp, runoffT,
                                                     bucket_cnt, e, nruns, nb);
        bucket_scan_kernel<<<1, 512, 0, stream>>>(bucket_cnt, bucket_base, nb, e);
        sort_buckets_kernel<<<nb, 256, 0, stream>>>(etmp, runoffT, bucket_base,
                                                    epack, row, n, e, nruns, nb);
        // etmp is dead now; its storage becomes A,B.
        gemm_dual_a<<<gemm_blocks, 128, 0, stream>>>(x, K1a, K2a, ba, A, B, n);
        gather_x1_kernel<<<gather_blocks, 256, 0, stream>>>(row, epack, A, B, Cg, n);
        gemm_dual_b<<<gemm_blocks, 128, 0, stream>>>(Cg, K1b, K2b, bb, A, B, n);
        gather_pool_kernel<<<gather_blocks, 256, 0, stream>>>(row, epack, A, B, pooled, n);
        dense_kernel<<<1, 64, 0, stream>>>(pooled, Wd1, bd1, Wd2, bd2, (float*)d_out);
    } else {
        // fallback: atomic scatter path
        float* A      = (float*)d_ws;
        float* B      = A + nc;
        float* Cg     = B + nc;
        float* pooled = Cg + nc;
        const int edge_blocks_8 = (int)(((long long)e * 8 + 255) / 256);

        hipMemsetAsync(Cg, 0, nc * 4, stream);
        gemm_dual_a<<<gemm_blocks, 128, 0, stream>>>(x, K1a, K2a, ba, A, B, n);
        edge_scatter<<<edge_blocks_8, 256, 0, stream>>>(esrc, edst, ew, A, Cg, e);
        relu_add_kernel<<<(int)((nc + 255) / 256), 256, 0, stream>>>(B, Cg, B, nc);
        gemm_dual_b<<<gemm_blocks, 128, 0, stream>>>(B, K1b, K2b, bb, A, Cg, n);
        hipMemsetAsync(B, 0, nc * 4, stream);
        edge_scatter<<<edge_blocks_8, 256, 0, stream>>>(esrc, edst, ew, A, B, e);
        hipMemsetAsync(pooled, 0, 32 * 4, stream);
        pool_kernel<<<1024, 256, 0, stream>>>(Cg, B, pooled, n);
        dense_kernel<<<1, 64, 0, stream>>>(pooled, Wd1, bd1, Wd2, bd2, (float*)d_out);
    }
}